// Round 3
// baseline (227.651 us; speedup 1.0000x reference)
//
#include <hip/hip_runtime.h>

// Problem constants (from reference):
//   B=16, S=4096, D_MODEL=512, PE_DIM=256, N_DIM_DIVIDE=2
// out[b,s,d] = x[b,s,d] + pe[s, d%256] + (s < L_b ? pe[L_b-1-s, 255-(d%256)] : 0)
// L_b = sum_s (mask[b,s] == 0)
//
// Single fused kernel: each block recomputes its batch's L_b directly from the
// mask (16 KB row, L1/L2-resident -> block-redundant reads are nearly free and
// fully overlap the HBM-bound streaming). This removes the separate lengths
// kernel launch + graph dependency edge.
//
// Layout: 256 threads = 4 waves; each wave covers 2 full 512-float rows.
// A wave's 64 lanes x float4 = 256 floats = one pe row, and d/d+256 share
// identical pe values, so each pe base/rev float4 is loaded once per row.
// x/out are pure streaming -> nontemporal; pe/mask are hot -> cached.

#define B_SZ   16
#define S_LEN  4096
#define D_MOD  512
#define PE_D   256

typedef float v4f __attribute__((ext_vector_type(4)));

__global__ __launch_bounds__(256) void pe_fused_kernel(
    const float* __restrict__ x, const int* __restrict__ mask,
    const float* __restrict__ pe, float* __restrict__ out)
{
    const int tid  = threadIdx.x;
    const int lane = tid & 63;
    const int wave = tid >> 6;
    const int b    = blockIdx.x >> 9;        // 8 rows/block -> 512 blocks/batch

    // ---- L_b from mask (block-redundant, L2-hot) ----
    const int4* m4 = reinterpret_cast<const int4*>(mask + (size_t)b * S_LEN);
    int cnt = 0;
    #pragma unroll
    for (int i = 0; i < 4; ++i) {            // 256 thr x 4 int4 = 4096 ints
        int4 v = m4[tid + i * 256];
        cnt += (v.x == 0) + (v.y == 0) + (v.z == 0) + (v.w == 0);
    }
    #pragma unroll
    for (int off = 32; off > 0; off >>= 1)
        cnt += __shfl_down(cnt, off, 64);
    __shared__ int wsum[4];
    if (lane == 0) wsum[wave] = cnt;
    __syncthreads();
    const int L = wsum[0] + wsum[1] + wsum[2] + wsum[3];   // broadcast

    // ---- fused add: wave handles rows r0 and r0+1 ----
    const long r0 = (long)blockIdx.x * 8 + wave * 2;
    const int d   = lane << 2;               // [0,256), mult of 4

    #pragma unroll
    for (int k = 0; k < 2; ++k) {
        const long row = r0 + k;
        const int s    = (int)(row & (S_LEN - 1));
        const long off = row * D_MOD + d;

        const v4f xv0 = __builtin_nontemporal_load(
            reinterpret_cast<const v4f*>(x + off));
        const v4f xv1 = __builtin_nontemporal_load(
            reinterpret_cast<const v4f*>(x + off + PE_D));
        const v4f pv = *reinterpret_cast<const v4f*>(pe + (size_t)s * PE_D + d);

        v4f r = {0.f, 0.f, 0.f, 0.f};
        if (s < L) {                         // wave-uniform branch
            const int idx = L - 1 - s;       // in [0, 4095]
            // pe[idx, 255-(d+j)], j=0..3 -> reversed float4 at 252-d
            const v4f rv = *reinterpret_cast<const v4f*>(
                pe + (size_t)idx * PE_D + (252 - d));
            r = (v4f){rv.w, rv.z, rv.y, rv.x};
        }

        // match reference association: (x + add_rev) + base
        v4f o0 = (xv0 + r) + pv;
        v4f o1 = (xv1 + r) + pv;
        __builtin_nontemporal_store(o0, reinterpret_cast<v4f*>(out + off));
        __builtin_nontemporal_store(o1, reinterpret_cast<v4f*>(out + off + PE_D));
    }
}

extern "C" void kernel_launch(void* const* d_in, const int* in_sizes, int n_in,
                              void* d_out, int out_size, void* d_ws, size_t ws_size,
                              hipStream_t stream)
{
    const float* x    = (const float*)d_in[0];   // (16, 4096, 512) fp32
    const int*   mask = (const int*)d_in[1];     // (16, 4096) int32
    const float* pe   = (const float*)d_in[2];   // (5000, 256) fp32
    float* out        = (float*)d_out;

    const int n_blocks = (B_SZ * S_LEN) / 8;     // 8192
    pe_fused_kernel<<<n_blocks, 256, 0, stream>>>(x, mask, pe, out);
}